// Round 1
// 4851.684 us; speedup vs baseline: 1.4693x; 1.4693x over previous
//
#include <hip/hip_runtime.h>

#define MFMA16 __builtin_amdgcn_mfma_f32_16x16x32_bf16

typedef __attribute__((ext_vector_type(8))) short short8;
typedef __attribute__((ext_vector_type(4))) float floatx4;

static constexpr int T_STEPS = 50;
static constexpr int BATCH   = 1024;
static constexpr int SDIM    = 32;
static constexpr int DDIM    = 600;
static constexpr int ADIM    = 6;
static constexpr int KP      = 608;   // padded K/N per gate
static constexpr int PITCH   = 616;   // LDS row pitch (shorts)
static constexpr int SAPITCH = 72;
static constexpr int NWAVES  = 10;
static constexpr int NTHREADS = 640;

// workspace layout (ushort offsets)
static constexpr size_t SZ608    = (size_t)608 * 608;
static constexpr size_t OFF_WIHR = 0;
static constexpr size_t OFF_WIHZ = OFF_WIHR + SZ608;
static constexpr size_t OFF_WIHN = OFF_WIHZ + SZ608;
static constexpr size_t OFF_WHHR = OFF_WIHN + SZ608;
static constexpr size_t OFF_WHHZ = OFF_WHHR + SZ608;
static constexpr size_t OFF_WHHN = OFF_WHHZ + SZ608;
static constexpr size_t OFF_WP1  = OFF_WHHN + SZ608;
static constexpr size_t OFF_WQ1D = OFF_WP1  + SZ608;
static constexpr size_t OFF_WQ1E = OFF_WQ1D + SZ608;              // [608][1024]
static constexpr size_t OFF_WSA  = OFF_WQ1E + (size_t)608 * 1024; // [608][64]
static constexpr size_t OFF_WHEAD= OFF_WSA  + (size_t)608 * 64;   // [128][608]
static constexpr size_t OFF_PREQ = OFF_WHEAD+ (size_t)128 * 608;  // [50*1024][600] bf16
static constexpr size_t OFF_DETG = OFF_PREQ + (size_t)T_STEPS * BATCH * 600; // [1024][608] bf16
static constexpr size_t OFF_BAR  = OFF_DETG + (size_t)BATCH * KP;            // 64 ints
static constexpr size_t OFF_PART = OFF_BAR + 256;                 // [64][4][16][128] f32

// output offsets (fp32 elements), reference return order
static constexpr size_t O_PM = 0;
static constexpr size_t O_PS = 1638400;
static constexpr size_t O_PR = 3276800;
static constexpr size_t O_D1 = 4915200;
static constexpr size_t O_QM = 35635200;
static constexpr size_t O_QS = 37273600;
static constexpr size_t O_PO = 38912000;
static constexpr size_t O_D2 = 40550400;

__device__ __forceinline__ unsigned short f2bf(float f) {
  unsigned u = __float_as_uint(f);
  u += 0x7FFFu + ((u >> 16) & 1u);   // RNE
  return (unsigned short)(u >> 16);
}
__device__ __forceinline__ float bf2f(unsigned short u) {
  return __uint_as_float(((unsigned)u) << 16);
}
__device__ __forceinline__ float elu_f(float v) { return v > 0.f ? v : expm1f(v); }
__device__ __forceinline__ float sigmoid_f(float x) { return 1.f / (1.f + expf(-x)); }
__device__ __forceinline__ float tanh_f(float x) {
  x = fminf(fmaxf(x, -15.f), 15.f);
  float e = expf(2.f * x);
  return (e - 1.f) / (e + 1.f);
}

// ---------------- prep: stage weights as bf16, padded/split per gate ----------------
__global__ __launch_bounds__(256) void stage_weights(
    const float* __restrict__ Win, const float* __restrict__ Wih, const float* __restrict__ Whh,
    const float* __restrict__ Wp1, const float* __restrict__ Wq1,
    const float* __restrict__ Wp2, const float* __restrict__ Wq2,
    unsigned short* __restrict__ ws)
{
  const int region = blockIdx.y;
  if (region == 11) {           // zero the per-bgroup barrier counters each launch
    if (blockIdx.x == 0 && threadIdx.x < 64)
      ((int*)(ws + OFF_BAR))[threadIdx.x] = 0;
    return;
  }
  int R = 608, C = 608;
  size_t dst = 0;
  switch (region) {
    case 0: dst = OFF_WIHR; break;
    case 1: dst = OFF_WIHZ; break;
    case 2: dst = OFF_WIHN; break;
    case 3: dst = OFF_WHHR; break;
    case 4: dst = OFF_WHHZ; break;
    case 5: dst = OFF_WHHN; break;
    case 6: dst = OFF_WP1;  break;
    case 7: dst = OFF_WQ1D; break;
    case 8: dst = OFF_WQ1E; C = 1024; break;
    case 9: dst = OFF_WSA;  C = 64;   break;
    case 10: dst = OFF_WHEAD; R = 128; break;
  }
  const int total = R * C;
  for (int e = blockIdx.x * 256 + threadIdx.x; e < total; e += gridDim.x * 256) {
    int n = e / C, k = e - n * C;
    float v = 0.f;
    switch (region) {
      case 0: if (n < 600 && k < 600) v = Wih[(size_t)n * 600 + k]; break;
      case 1: if (n < 600 && k < 600) v = Wih[(size_t)(600 + n) * 600 + k]; break;
      case 2: if (n < 600 && k < 600) v = Wih[(size_t)(1200 + n) * 600 + k]; break;
      case 3: if (n < 600 && k < 600) v = Whh[(size_t)n * 600 + k]; break;
      case 4: if (n < 600 && k < 600) v = Whh[(size_t)(600 + n) * 600 + k]; break;
      case 5: if (n < 600 && k < 600) v = Whh[(size_t)(1200 + n) * 600 + k]; break;
      case 6: if (n < 600 && k < 600) v = Wp1[(size_t)n * 600 + k]; break;
      case 7: if (n < 600 && k < 600) v = Wq1[(size_t)n * 1624 + k]; break;
      case 8: if (n < 600) v = Wq1[(size_t)n * 1624 + 600 + k]; break;
      case 9: if (n < 600) { if (k < 32) v = Win[(size_t)n * 38 + 6 + k];
                             else if (k < 38) v = Win[(size_t)n * 38 + (k - 32)]; } break;
      case 10: if (k < 600) v = (n < 64) ? Wp2[(size_t)n * 600 + k]
                                         : Wq2[(size_t)(n - 64) * 600 + k]; break;
    }
    ws[dst + (size_t)e] = f2bf(v);
  }
}

// ---------------- prep: pre_q[t,b,:] = enc[t,b,:] @ Wq1[:,600:].T + bq1 (bf16 out) ----------------
__global__ __launch_bounds__(256) void preq_gemm(
    const float* __restrict__ enc, const float* __restrict__ bq1,
    const unsigned short* __restrict__ ws, unsigned short* __restrict__ preq)
{
  __shared__ unsigned short A[16 * 1032];
  const size_t g0 = (size_t)blockIdx.x * 16;
  const int tid = threadIdx.x;

  const float4* e4 = (const float4*)(enc + g0 * 1024);
  for (int i = tid; i < 16 * 256; i += 256) {
    int row = i >> 8, c4 = i & 255;
    float4 v = e4[row * 256 + c4];
    int base = row * 1032 + c4 * 4;
    A[base + 0] = f2bf(v.x); A[base + 1] = f2bf(v.y);
    A[base + 2] = f2bf(v.z); A[base + 3] = f2bf(v.w);
  }
  __syncthreads();

  const int wave = tid >> 6, lane = tid & 63, q = lane >> 4, l15 = lane & 15;
  const unsigned short* Wq1e = ws + OFF_WQ1E;
  for (int tile = wave; tile < 38; tile += 4) {
    const int n0 = tile * 16;
    floatx4 acc = {0.f, 0.f, 0.f, 0.f};
    const unsigned short* wb = Wq1e + (size_t)(n0 + l15) * 1024 + q * 8;
    const int aoff = l15 * 1032 + q * 8;
    for (int ki = 0; ki < 32; ++ki) {
      short8 a = *(const short8*)(&A[aoff + ki * 32]);
      short8 b = *(const short8*)(wb + ki * 32);
      acc = MFMA16(a, b, acc, 0, 0, 0);
    }
    const int col = n0 + l15;
    if (col < 600) {
      float bb = bq1[col];
      for (int i = 0; i < 4; ++i) {
        int row = q * 4 + i;
        preq[(g0 + row) * 600 + col] = f2bf(acc[i] + bb);
      }
    }
  }
}

// ---------------- main rollout: 256 wgs = 64 batch-groups x 4 N-slices ----------------
// slice = wgid & 3  (XCD = wgid % 8 round-robin -> each XCD holds one slice's weights, L2-resident)
// per step: [reduce prev heads -> SA] P0b(full, redundant) | P1 GRU(slice) -> DETG | bg-sync |
//           load DETG->LDS | P2 h_p/h_q(slice) | P3 head K-partials -> PART | bg-sync
__global__ __launch_bounds__(NTHREADS) void rssm_rollout(
    const float* __restrict__ actions, const float* __restrict__ init_stoch,
    const float* __restrict__ init_det,
    const float* __restrict__ eps_p, const float* __restrict__ eps_q,
    const float* __restrict__ b_in, const float* __restrict__ b_ih, const float* __restrict__ b_hh,
    const float* __restrict__ bp1, const float* __restrict__ bp2, const float* __restrict__ bq2,
    unsigned short* __restrict__ wsm, float* __restrict__ out)
{
  __shared__ unsigned short XB[16 * PITCH];   // rnn_in; overwritten with h_p in P2
  __shared__ unsigned short DC[16 * PITCH];   // det (old; refreshed to det_new after sync A)
  __shared__ unsigned short HQ[16 * PITCH];   // h_q
  __shared__ unsigned short SA[16 * SAPITCH]; // [stoch(32)|act(6)|pad] bf16

  const unsigned short* ws = wsm;
  const int tid  = threadIdx.x;
  const int wave = tid >> 6, lane = tid & 63, q = lane >> 4, l15 = lane & 15;
  const int wg    = blockIdx.x;
  const int slice = wg & 3;
  const int bg    = wg >> 2;
  const int brow0 = bg * 16;
  const int ntile = (slice < 3) ? 10 : 8;     // col tiles: contiguous 10/10/10/8 (= 38)
  const int tile0 = slice * 10;
  const int cs    = slice * 160;              // owned col base (slice3: 480..607, 600+ zero)

  unsigned short* DETG = wsm + OFF_DETG;
  int*   bar  = (int*)(wsm + OFF_BAR);
  float* PART = (float*)(wsm + OFF_PART);
  const unsigned short* preq = ws + OFF_PREQ;

  float* out_pm = out + O_PM; float* out_ps = out + O_PS; float* out_pr = out + O_PR;
  float* out_d1 = out + O_D1; float* out_qm = out + O_QM; float* out_qs = out + O_QS;
  float* out_po = out + O_PO; float* out_d2 = out + O_D2;

  int phase = 0;
  auto bgsync = [&]() {   // 4-wg barrier per batch-group, device scope
    __syncthreads();
    ++phase;
    if (tid == 0) {
      __threadfence();
      __hip_atomic_fetch_add(&bar[bg], 1, __ATOMIC_RELEASE, __HIP_MEMORY_SCOPE_AGENT);
      while (__hip_atomic_load(&bar[bg], __ATOMIC_ACQUIRE, __HIP_MEMORY_SCOPE_AGENT) < 4 * phase)
        __builtin_amdgcn_s_sleep(2);
    }
    __syncthreads();
  };

  auto do_reduce = [&](int tcur) {  // combine head partials of step (tcur-1); fill SA; write outs
    const float* part = PART + (size_t)bg * (4 * 16 * 128);
    if (tid < 512) {
      const int r = tid >> 5, c = tid & 31;
      float pm = bp2[c], psr = bp2[32 + c];
      float qm = bq2[c], qsr = bq2[32 + c];
      for (int s2 = 0; s2 < 4; ++s2) {
        const float* p = part + (s2 * 16 + r) * 128;
        pm += p[c];       psr += p[32 + c];
        qm += p[64 + c];  qsr += p[96 + c];
      }
      const size_t oidx = ((size_t)(tcur - 1) * BATCH + brow0 + r) * SDIM + c;
      const float qs = (qsr > 30.f ? qsr : log1pf(expf(qsr))) + 0.1f;
      const float x  = qm + qs * eps_q[oidx];
      SA[r * SAPITCH + c] = f2bf(x);          // stoch carry
      if (slice == 0) {
        const float ps = (psr > 30.f ? psr : log1pf(expf(psr))) + 0.1f;
        out_pm[oidx] = pm; out_ps[oidx] = ps; out_pr[oidx] = pm + ps * eps_p[oidx];
      } else if (slice == 1) {
        out_qm[oidx] = qm; out_qs[oidx] = qs; out_po[oidx] = x;
      }
    }
  };

  for (int t = 0; t < T_STEPS; ++t) {
    // ---- top of step: SA fill (init or reduce of prev heads) + stage act[t]
    if (t == 0) {
      for (int i = tid; i < 16 * PITCH; i += NTHREADS) { XB[i] = 0; DC[i] = 0; HQ[i] = 0; }
      for (int i = tid; i < 16 * SAPITCH; i += NTHREADS) SA[i] = 0;
      __syncthreads();
      for (int i = tid; i < 16 * SDIM; i += NTHREADS) {
        int r = i >> 5, c = i & 31;
        SA[r * SAPITCH + c] = f2bf(init_stoch[(size_t)(brow0 + r) * SDIM + c]);
      }
      for (int i = tid; i < 16 * DDIM; i += NTHREADS) {
        int r = i / DDIM, k = i - r * DDIM;
        DC[r * PITCH + k] = f2bf(init_det[(size_t)(brow0 + r) * DDIM + k]);
      }
      if (tid < 128) {  // zero DETG pad cols (600..607) for this bgroup
        int r = tid >> 3, c = 600 + (tid & 7);
        DETG[(size_t)(brow0 + r) * KP + c] = 0;
      }
    } else {
      do_reduce(t);
    }
    if (tid < 96) {
      int r = tid / 6, j = tid - r * 6;
      SA[r * SAPITCH + 32 + j] = f2bf(actions[((size_t)t * BATCH + brow0 + r) * ADIM + j]);
    }
    __syncthreads();

    // ---- P0b: rnn_in = elu([stoch|act] @ Wsa.T + b_in) -> XB, full width (cheap, redundant)
    for (int tile = wave; tile < 38; tile += NWAVES) {
      const int n0 = tile * 16;
      floatx4 acc = {0.f, 0.f, 0.f, 0.f};
      const unsigned short* wb = ws + OFF_WSA + (size_t)(n0 + l15) * 64 + q * 8;
      const int aoff = l15 * SAPITCH + q * 8;
      acc = MFMA16(*(const short8*)(&SA[aoff]),      *(const short8*)(wb),      acc, 0, 0, 0);
      acc = MFMA16(*(const short8*)(&SA[aoff + 32]), *(const short8*)(wb + 32), acc, 0, 0, 0);
      const int col = n0 + l15;
      if (col < DDIM) {
        float bi = b_in[col];
        for (int i = 0; i < 4; ++i)
          XB[(q * 4 + i) * PITCH + col] = f2bf(elu_f(acc[i] + bi));
      }
    }
    __syncthreads();

    // ---- P1: GRU for owned col tiles -> DETG + outputs d1/d2
    if (wave < ntile) {
      const int n0 = (tile0 + wave) * 16;
      floatx4 aIr = {0,0,0,0}, aIz = {0,0,0,0}, aIn = {0,0,0,0};
      floatx4 aHr = {0,0,0,0}, aHz = {0,0,0,0}, aHn = {0,0,0,0};
      const size_t wrow = (size_t)(n0 + l15) * KP + q * 8;
      const unsigned short* pIr = ws + OFF_WIHR + wrow;
      const unsigned short* pIz = ws + OFF_WIHZ + wrow;
      const unsigned short* pIn = ws + OFF_WIHN + wrow;
      const unsigned short* pHr = ws + OFF_WHHR + wrow;
      const unsigned short* pHz = ws + OFF_WHHZ + wrow;
      const unsigned short* pHn = ws + OFF_WHHN + wrow;
      const int aoff = l15 * PITCH + q * 8;
      for (int ki = 0; ki < 19; ++ki) {
        short8 ax = *(const short8*)(&XB[aoff + ki * 32]);
        short8 ad = *(const short8*)(&DC[aoff + ki * 32]);
        aIr = MFMA16(ax, *(const short8*)(pIr + ki * 32), aIr, 0, 0, 0);
        aIz = MFMA16(ax, *(const short8*)(pIz + ki * 32), aIz, 0, 0, 0);
        aIn = MFMA16(ax, *(const short8*)(pIn + ki * 32), aIn, 0, 0, 0);
        aHr = MFMA16(ad, *(const short8*)(pHr + ki * 32), aHr, 0, 0, 0);
        aHz = MFMA16(ad, *(const short8*)(pHz + ki * 32), aHz, 0, 0, 0);
        aHn = MFMA16(ad, *(const short8*)(pHn + ki * 32), aHn, 0, 0, 0);
      }
      const int d = n0 + l15;
      if (d < DDIM) {
        float bihr = b_ih[d],        bhhr = b_hh[d];
        float bihz = b_ih[600 + d],  bhhz = b_hh[600 + d];
        float bihn = b_ih[1200 + d], bhhn = b_hh[1200 + d];
        for (int i = 0; i < 4; ++i) {
          int row = q * 4 + i;
          float r = sigmoid_f(aIr[i] + aHr[i] + bihr + bhhr);
          float z = sigmoid_f(aIz[i] + aHz[i] + bihz + bhhz);
          float n = tanh_f(aIn[i] + bihn + r * (aHn[i] + bhhn));
          float dprev = bf2f(DC[row * PITCH + d]);
          float dn = (1.f - z) * n + z * dprev;
          DETG[(size_t)(brow0 + row) * KP + d] = f2bf(dn);
          size_t oidx = ((size_t)t * BATCH + brow0 + row) * DDIM + d;
          out_d1[oidx] = dn;
          out_d2[oidx] = dn;
        }
      }
    }
    bgsync();   // sync A: det_new complete across the bgroup's 4 slices

    // ---- load full det_new -> DC (also serves as det_old for next step's P1)
    {
      const uint2* src = (const uint2*)DETG;   // 608 shorts = 152 x 8B per row
      for (int i = tid; i < 16 * 152; i += NTHREADS) {
        int r = i / 152, c = i - r * 152;
        *(uint2*)(&DC[r * PITCH + c * 4]) = src[(size_t)(brow0 + r) * 152 + c];
      }
    }
    __syncthreads();

    // ---- P2: h_p -> XB, h_q -> HQ for owned tiles
    if (wave < ntile) {
      const int n0 = (tile0 + wave) * 16;
      floatx4 accP = {0,0,0,0}, accQ = {0,0,0,0};
      const size_t wrow = (size_t)(n0 + l15) * KP + q * 8;
      const unsigned short* pP = ws + OFF_WP1  + wrow;
      const unsigned short* pQ = ws + OFF_WQ1D + wrow;
      const int aoff = l15 * PITCH + q * 8;
      for (int ki = 0; ki < 19; ++ki) {
        short8 a = *(const short8*)(&DC[aoff + ki * 32]);
        accP = MFMA16(a, *(const short8*)(pP + ki * 32), accP, 0, 0, 0);
        accQ = MFMA16(a, *(const short8*)(pQ + ki * 32), accQ, 0, 0, 0);
      }
      const int col = n0 + l15;
      if (col < DDIM) {
        float bb = bp1[col];
        for (int i = 0; i < 4; ++i) {
          int row = q * 4 + i;
          XB[row * PITCH + col] = f2bf(elu_f(accP[i] + bb));
          float pre = bf2f(preq[((size_t)t * BATCH + brow0 + row) * 600 + col]);
          HQ[row * PITCH + col] = f2bf(elu_f(accQ[i] + pre));
        }
      }
    }
    __syncthreads();

    // ---- P3: head K-partials over owned cols -> PART[bg][slice][16][128]
    if (wave < 8) {
      const int h0 = wave * 16;                       // head rows: 0-63 prior, 64-127 post
      const unsigned short* Asrc = (wave < 4) ? XB : HQ;
      const int nk = (slice < 3) ? 5 : 4;             // 160 / 128 owned cols
      floatx4 acc = {0,0,0,0};
      const unsigned short* pW = ws + OFF_WHEAD + (size_t)(h0 + l15) * KP + cs + q * 8;
      const int abase = l15 * PITCH + cs + q * 8;
      for (int kk = 0; kk < nk; ++kk) {
        acc = MFMA16(*(const short8*)(&Asrc[abase + kk * 32]),
                     *(const short8*)(pW + kk * 32), acc, 0, 0, 0);
      }
      float* pdst = PART + (size_t)(bg * 4 + slice) * (16 * 128);
      for (int i = 0; i < 4; ++i)
        pdst[(q * 4 + i) * 128 + h0 + l15] = acc[i];
    }
    bgsync();   // sync B: partials visible for next step's reduce
  }

  do_reduce(T_STEPS);   // emit final step's head outputs
}

extern "C" void kernel_launch(void* const* d_in, const int* in_sizes, int n_in,
                              void* d_out, int out_size, void* d_ws, size_t ws_size,
                              hipStream_t stream) {
  const float* enc    = (const float*)d_in[1];
  const float* act    = (const float*)d_in[2];
  const float* init_s = (const float*)d_in[3];
  const float* init_d = (const float*)d_in[4];
  const float* np_    = (const float*)d_in[5];
  const float* nq_    = (const float*)d_in[6];
  const float* Win    = (const float*)d_in[7];
  const float* b_in   = (const float*)d_in[8];
  const float* Wih    = (const float*)d_in[9];
  const float* Whh    = (const float*)d_in[10];
  const float* bih    = (const float*)d_in[11];
  const float* bhh    = (const float*)d_in[12];
  const float* Wp1    = (const float*)d_in[13];
  const float* bp1    = (const float*)d_in[14];
  const float* Wp2    = (const float*)d_in[15];
  const float* bp2    = (const float*)d_in[16];
  const float* Wq1    = (const float*)d_in[17];
  const float* bq1    = (const float*)d_in[18];
  const float* Wq2    = (const float*)d_in[19];
  const float* bq2    = (const float*)d_in[20];
  unsigned short* ws  = (unsigned short*)d_ws;
  float* out = (float*)d_out;

  stage_weights<<<dim3(256, 12), 256, 0, stream>>>(Win, Wih, Whh, Wp1, Wq1, Wp2, Wq2, ws);
  preq_gemm<<<3200, 256, 0, stream>>>(enc, bq1, ws, ws + OFF_PREQ);
  rssm_rollout<<<256, NTHREADS, 0, stream>>>(act, init_s, init_d, np_, nq_,
                                             b_in, bih, bhh, bp1, bp2, bq2, ws, out);
}

// Round 2
// 4024.922 us; speedup vs baseline: 1.7711x; 1.2054x over previous
//
#include <hip/hip_runtime.h>

#define MFMA16 __builtin_amdgcn_mfma_f32_16x16x32_bf16

typedef __attribute__((ext_vector_type(8))) short short8;
typedef __attribute__((ext_vector_type(4))) float floatx4;

static constexpr int T_STEPS = 50;
static constexpr int BATCH   = 1024;
static constexpr int SDIM    = 32;
static constexpr int DDIM    = 600;
static constexpr int ADIM    = 6;
static constexpr int KP      = 608;   // padded K/N per gate
static constexpr int PITCH   = 616;   // LDS row pitch (shorts)
static constexpr int SAPITCH = 72;
static constexpr int NWAVES  = 10;
static constexpr int NTHREADS = 640;

// workspace layout (ushort offsets)
static constexpr size_t SZ608    = (size_t)608 * 608;
static constexpr size_t OFF_WIHR = 0;
static constexpr size_t OFF_WIHZ = OFF_WIHR + SZ608;
static constexpr size_t OFF_WIHN = OFF_WIHZ + SZ608;
static constexpr size_t OFF_WHHR = OFF_WIHN + SZ608;
static constexpr size_t OFF_WHHZ = OFF_WHHR + SZ608;
static constexpr size_t OFF_WHHN = OFF_WHHZ + SZ608;
static constexpr size_t OFF_WP1  = OFF_WHHN + SZ608;
static constexpr size_t OFF_WQ1D = OFF_WP1  + SZ608;
static constexpr size_t OFF_WQ1E = OFF_WQ1D + SZ608;              // [608][1024]
static constexpr size_t OFF_WSA  = OFF_WQ1E + (size_t)608 * 1024; // [608][64]
static constexpr size_t OFF_WHEAD= OFF_WSA  + (size_t)608 * 64;   // [128][608]
static constexpr size_t OFF_PREQ = OFF_WHEAD+ (size_t)128 * 608;  // [50*1024][600] bf16
static constexpr size_t OFF_DETG = OFF_PREQ + (size_t)T_STEPS * BATCH * 600; // [1024][608] bf16
static constexpr size_t OFF_BAR  = OFF_DETG + (size_t)BATCH * KP;            // 64 ints
static constexpr size_t OFF_PART = OFF_BAR + 256;                 // [64][4][16][128] f32

// output offsets (fp32 elements), reference return order
static constexpr size_t O_PM = 0;
static constexpr size_t O_PS = 1638400;
static constexpr size_t O_PR = 3276800;
static constexpr size_t O_D1 = 4915200;
static constexpr size_t O_QM = 35635200;
static constexpr size_t O_QS = 37273600;
static constexpr size_t O_PO = 38912000;
static constexpr size_t O_D2 = 40550400;

__device__ __forceinline__ unsigned short f2bf(float f) {
  unsigned u = __float_as_uint(f);
  u += 0x7FFFu + ((u >> 16) & 1u);   // RNE
  return (unsigned short)(u >> 16);
}
__device__ __forceinline__ float bf2f(unsigned short u) {
  return __uint_as_float(((unsigned)u) << 16);
}
__device__ __forceinline__ float elu_f(float v) { return v > 0.f ? v : expm1f(v); }
__device__ __forceinline__ float sigmoid_f(float x) { return 1.f / (1.f + expf(-x)); }
__device__ __forceinline__ float tanh_f(float x) {
  x = fminf(fmaxf(x, -15.f), 15.f);
  float e = expf(2.f * x);
  return (e - 1.f) / (e + 1.f);
}

// ---------------- prep: stage weights as bf16, padded/split per gate ----------------
__global__ __launch_bounds__(256) void stage_weights(
    const float* __restrict__ Win, const float* __restrict__ Wih, const float* __restrict__ Whh,
    const float* __restrict__ Wp1, const float* __restrict__ Wq1,
    const float* __restrict__ Wp2, const float* __restrict__ Wq2,
    unsigned short* __restrict__ ws)
{
  const int region = blockIdx.y;
  if (region == 11) {           // zero the per-bgroup barrier counters each launch
    if (blockIdx.x == 0 && threadIdx.x < 64)
      ((int*)(ws + OFF_BAR))[threadIdx.x] = 0;
    return;
  }
  int R = 608, C = 608;
  size_t dst = 0;
  switch (region) {
    case 0: dst = OFF_WIHR; break;
    case 1: dst = OFF_WIHZ; break;
    case 2: dst = OFF_WIHN; break;
    case 3: dst = OFF_WHHR; break;
    case 4: dst = OFF_WHHZ; break;
    case 5: dst = OFF_WHHN; break;
    case 6: dst = OFF_WP1;  break;
    case 7: dst = OFF_WQ1D; break;
    case 8: dst = OFF_WQ1E; C = 1024; break;
    case 9: dst = OFF_WSA;  C = 64;   break;
    case 10: dst = OFF_WHEAD; R = 128; break;
  }
  const int total = R * C;
  for (int e = blockIdx.x * 256 + threadIdx.x; e < total; e += gridDim.x * 256) {
    int n = e / C, k = e - n * C;
    float v = 0.f;
    switch (region) {
      case 0: if (n < 600 && k < 600) v = Wih[(size_t)n * 600 + k]; break;
      case 1: if (n < 600 && k < 600) v = Wih[(size_t)(600 + n) * 600 + k]; break;
      case 2: if (n < 600 && k < 600) v = Wih[(size_t)(1200 + n) * 600 + k]; break;
      case 3: if (n < 600 && k < 600) v = Whh[(size_t)n * 600 + k]; break;
      case 4: if (n < 600 && k < 600) v = Whh[(size_t)(600 + n) * 600 + k]; break;
      case 5: if (n < 600 && k < 600) v = Whh[(size_t)(1200 + n) * 600 + k]; break;
      case 6: if (n < 600 && k < 600) v = Wp1[(size_t)n * 600 + k]; break;
      case 7: if (n < 600 && k < 600) v = Wq1[(size_t)n * 1624 + k]; break;
      case 8: if (n < 600) v = Wq1[(size_t)n * 1624 + 600 + k]; break;
      case 9: if (n < 600) { if (k < 32) v = Win[(size_t)n * 38 + 6 + k];
                             else if (k < 38) v = Win[(size_t)n * 38 + (k - 32)]; } break;
      case 10: if (k < 600) v = (n < 64) ? Wp2[(size_t)n * 600 + k]
                                         : Wq2[(size_t)(n - 64) * 600 + k]; break;
    }
    ws[dst + (size_t)e] = f2bf(v);
  }
}

// ---------------- prep: pre_q[t,b,:] = enc[t,b,:] @ Wq1[:,600:].T + bq1 (bf16 out) ----------------
__global__ __launch_bounds__(256) void preq_gemm(
    const float* __restrict__ enc, const float* __restrict__ bq1,
    const unsigned short* __restrict__ ws, unsigned short* __restrict__ preq)
{
  __shared__ unsigned short A[16 * 1032];
  const size_t g0 = (size_t)blockIdx.x * 16;
  const int tid = threadIdx.x;

  const float4* e4 = (const float4*)(enc + g0 * 1024);
  for (int i = tid; i < 16 * 256; i += 256) {
    int row = i >> 8, c4 = i & 255;
    float4 v = e4[row * 256 + c4];
    int base = row * 1032 + c4 * 4;
    A[base + 0] = f2bf(v.x); A[base + 1] = f2bf(v.y);
    A[base + 2] = f2bf(v.z); A[base + 3] = f2bf(v.w);
  }
  __syncthreads();

  const int wave = tid >> 6, lane = tid & 63, q = lane >> 4, l15 = lane & 15;
  const unsigned short* Wq1e = ws + OFF_WQ1E;
  for (int tile = wave; tile < 38; tile += 4) {
    const int n0 = tile * 16;
    floatx4 acc = {0.f, 0.f, 0.f, 0.f};
    const unsigned short* wb = Wq1e + (size_t)(n0 + l15) * 1024 + q * 8;
    const int aoff = l15 * 1032 + q * 8;
    for (int ki = 0; ki < 32; ++ki) {
      short8 a = *(const short8*)(&A[aoff + ki * 32]);
      short8 b = *(const short8*)(wb + ki * 32);
      acc = MFMA16(a, b, acc, 0, 0, 0);
    }
    const int col = n0 + l15;
    if (col < 600) {
      float bb = bq1[col];
      for (int i = 0; i < 4; ++i) {
        int row = q * 4 + i;
        preq[(g0 + row) * 600 + col] = f2bf(acc[i] + bb);
      }
    }
  }
}

// ---------------- main rollout: 256 wgs = 64 batch-groups x 4 N-slices ----------------
// slice = wgid & 3  -> XCD k hosts only slice k&3: slice weights stay L2-resident.
// Cross-XCD communication (DETG, PART) uses volatile (sc0+sc1, LLC-coherent) accesses,
// barrier flags use RELAXED device-scope atomics: NO buffer_inv/wbl2 cache nukes.
__global__ __launch_bounds__(NTHREADS)
__attribute__((amdgpu_waves_per_eu(3)))
void rssm_rollout(
    const float* __restrict__ actions, const float* __restrict__ init_stoch,
    const float* __restrict__ init_det,
    const float* __restrict__ eps_p, const float* __restrict__ eps_q,
    const float* __restrict__ b_in, const float* __restrict__ b_ih, const float* __restrict__ b_hh,
    const float* __restrict__ bp1, const float* __restrict__ bp2, const float* __restrict__ bq2,
    unsigned short* __restrict__ wsm, float* __restrict__ out)
{
  __shared__ unsigned short XB[16 * PITCH];   // rnn_in; overwritten with h_p in P2
  __shared__ unsigned short DC[16 * PITCH];   // det (old; refreshed to det_new after sync A)
  __shared__ unsigned short HQ[16 * PITCH];   // h_q
  __shared__ unsigned short SA[16 * SAPITCH]; // [stoch(32)|act(6)|pad] bf16

  const unsigned short* ws = wsm;
  const int tid  = threadIdx.x;
  const int wave = tid >> 6, lane = tid & 63, q = lane >> 4, l15 = lane & 15;
  const int wg    = blockIdx.x;
  const int slice = wg & 3;
  const int bg    = wg >> 2;
  const int brow0 = bg * 16;
  const int ntile = (slice < 3) ? 10 : 8;     // col tiles: contiguous 10/10/10/8 (= 38)
  const int tile0 = slice * 10;
  const int cs    = slice * 160;              // owned col base

  unsigned short* DETG = wsm + OFF_DETG;
  int*   bar  = (int*)(wsm + OFF_BAR);
  float* PART = (float*)(wsm + OFF_PART);
  const unsigned short* preq = ws + OFF_PREQ;

  float* out_pm = out + O_PM; float* out_ps = out + O_PS; float* out_pr = out + O_PR;
  float* out_d1 = out + O_D1; float* out_qm = out + O_QM; float* out_qs = out + O_QS;
  float* out_po = out + O_PO; float* out_d2 = out + O_D2;

  int phase = 0;
  auto bgsync = [&]() {   // 4-wg barrier per batch-group, RELAXED (no cache maintenance).
    // __syncthreads() drains vmcnt(0) for every wave -> all volatile stores are at the
    // coherence point (LLC) before tid0 signals. Data reads on the far side are volatile,
    // so no acquire-invalidate is needed.
    __syncthreads();
    ++phase;
    if (tid == 0) {
      __hip_atomic_fetch_add(&bar[bg], 1, __ATOMIC_RELAXED, __HIP_MEMORY_SCOPE_AGENT);
      while (__hip_atomic_load(&bar[bg], __ATOMIC_RELAXED, __HIP_MEMORY_SCOPE_AGENT) < 4 * phase)
        __builtin_amdgcn_s_sleep(2);
    }
    __syncthreads();
    asm volatile("" ::: "memory");
  };

  auto do_reduce = [&](int tcur) {  // combine head partials of step (tcur-1); fill SA; write outs
    const volatile float* part = (const volatile float*)(PART + (size_t)bg * (4 * 16 * 128));
    if (tid < 512) {
      const int r = tid >> 5, c = tid & 31;
      float pm = bp2[c], psr = bp2[32 + c];
      float qm = bq2[c], qsr = bq2[32 + c];
      for (int s2 = 0; s2 < 4; ++s2) {
        const volatile float* p = part + (s2 * 16 + r) * 128;
        pm += p[c];       psr += p[32 + c];
        qm += p[64 + c];  qsr += p[96 + c];
      }
      const size_t oidx = ((size_t)(tcur - 1) * BATCH + brow0 + r) * SDIM + c;
      const float qs = (qsr > 30.f ? qsr : log1pf(expf(qsr))) + 0.1f;
      const float x  = qm + qs * eps_q[oidx];
      SA[r * SAPITCH + c] = f2bf(x);          // stoch carry
      if (slice == 0) {
        const float ps = (psr > 30.f ? psr : log1pf(expf(psr))) + 0.1f;
        out_pm[oidx] = pm; out_ps[oidx] = ps; out_pr[oidx] = pm + ps * eps_p[oidx];
      } else if (slice == 1) {
        out_qm[oidx] = qm; out_qs[oidx] = qs; out_po[oidx] = x;
      }
    }
  };

  for (int t = 0; t < T_STEPS; ++t) {
    // ---- top of step: SA fill (init or reduce of prev heads) + stage act[t]
    if (t == 0) {
      for (int i = tid; i < 16 * PITCH; i += NTHREADS) { XB[i] = 0; DC[i] = 0; HQ[i] = 0; }
      for (int i = tid; i < 16 * SAPITCH; i += NTHREADS) SA[i] = 0;
      __syncthreads();
      for (int i = tid; i < 16 * SDIM; i += NTHREADS) {
        int r = i >> 5, c = i & 31;
        SA[r * SAPITCH + c] = f2bf(init_stoch[(size_t)(brow0 + r) * SDIM + c]);
      }
      for (int i = tid; i < 16 * DDIM; i += NTHREADS) {
        int r = i / DDIM, k = i - r * DDIM;
        DC[r * PITCH + k] = f2bf(init_det[(size_t)(brow0 + r) * DDIM + k]);
      }
      if (tid < 128) {  // zero DETG pad cols (600..607) for this bgroup
        int r = tid >> 3, c = 600 + (tid & 7);
        *(volatile unsigned short*)&DETG[(size_t)(brow0 + r) * KP + c] = 0;
      }
    } else {
      do_reduce(t);
    }
    if (tid < 96) {
      int r = tid / 6, j = tid - r * 6;
      SA[r * SAPITCH + 32 + j] = f2bf(actions[((size_t)t * BATCH + brow0 + r) * ADIM + j]);
    }
    __syncthreads();

    // ---- P0b: rnn_in = elu([stoch|act] @ Wsa.T + b_in) -> XB, full width (cheap, redundant)
    for (int tile = wave; tile < 38; tile += NWAVES) {
      const int n0 = tile * 16;
      floatx4 acc = {0.f, 0.f, 0.f, 0.f};
      const unsigned short* wb = ws + OFF_WSA + (size_t)(n0 + l15) * 64 + q * 8;
      const int aoff = l15 * SAPITCH + q * 8;
      acc = MFMA16(*(const short8*)(&SA[aoff]),      *(const short8*)(wb),      acc, 0, 0, 0);
      acc = MFMA16(*(const short8*)(&SA[aoff + 32]), *(const short8*)(wb + 32), acc, 0, 0, 0);
      const int col = n0 + l15;
      if (col < DDIM) {
        float bi = b_in[col];
        for (int i = 0; i < 4; ++i)
          XB[(q * 4 + i) * PITCH + col] = f2bf(elu_f(acc[i] + bi));
      }
    }
    __syncthreads();

    // ---- P1: GRU for owned col tiles -> DETG + outputs d1/d2
    if (wave < ntile) {
      const int n0 = (tile0 + wave) * 16;
      floatx4 aIr = {0,0,0,0}, aIz = {0,0,0,0}, aIn = {0,0,0,0};
      floatx4 aHr = {0,0,0,0}, aHz = {0,0,0,0}, aHn = {0,0,0,0};
      const size_t wrow = (size_t)(n0 + l15) * KP + q * 8;
      const unsigned short* pIr = ws + OFF_WIHR + wrow;
      const unsigned short* pIz = ws + OFF_WIHZ + wrow;
      const unsigned short* pIn = ws + OFF_WIHN + wrow;
      const unsigned short* pHr = ws + OFF_WHHR + wrow;
      const unsigned short* pHz = ws + OFF_WHHZ + wrow;
      const unsigned short* pHn = ws + OFF_WHHN + wrow;
      const int aoff = l15 * PITCH + q * 8;
      #pragma unroll 4
      for (int ki = 0; ki < 19; ++ki) {
        short8 ax = *(const short8*)(&XB[aoff + ki * 32]);
        short8 ad = *(const short8*)(&DC[aoff + ki * 32]);
        aIr = MFMA16(ax, *(const short8*)(pIr + ki * 32), aIr, 0, 0, 0);
        aIz = MFMA16(ax, *(const short8*)(pIz + ki * 32), aIz, 0, 0, 0);
        aIn = MFMA16(ax, *(const short8*)(pIn + ki * 32), aIn, 0, 0, 0);
        aHr = MFMA16(ad, *(const short8*)(pHr + ki * 32), aHr, 0, 0, 0);
        aHz = MFMA16(ad, *(const short8*)(pHz + ki * 32), aHz, 0, 0, 0);
        aHn = MFMA16(ad, *(const short8*)(pHn + ki * 32), aHn, 0, 0, 0);
      }
      const int d = n0 + l15;
      if (d < DDIM) {
        float bihr = b_ih[d],        bhhr = b_hh[d];
        float bihz = b_ih[600 + d],  bhhz = b_hh[600 + d];
        float bihn = b_ih[1200 + d], bhhn = b_hh[1200 + d];
        for (int i = 0; i < 4; ++i) {
          int row = q * 4 + i;
          float r = sigmoid_f(aIr[i] + aHr[i] + bihr + bhhr);
          float z = sigmoid_f(aIz[i] + aHz[i] + bihz + bhhz);
          float n = tanh_f(aIn[i] + bihn + r * (aHn[i] + bhhn));
          float dprev = bf2f(DC[row * PITCH + d]);
          float dn = (1.f - z) * n + z * dprev;
          *(volatile unsigned short*)&DETG[(size_t)(brow0 + row) * KP + d] = f2bf(dn);
          size_t oidx = ((size_t)t * BATCH + brow0 + row) * DDIM + d;
          out_d1[oidx] = dn;
          out_d2[oidx] = dn;
        }
      }
    }
    bgsync();   // sync A: det_new complete across the bgroup's 4 slices

    // ---- load full det_new -> DC (also serves as det_old for next step's P1)
    {
      const volatile unsigned long long* src =
          (const volatile unsigned long long*)DETG;   // 608 shorts = 152 x 8B per row
      for (int i = tid; i < 16 * 152; i += NTHREADS) {
        int r = i / 152, c = i - r * 152;
        *(unsigned long long*)(&DC[r * PITCH + c * 4]) = src[(size_t)(brow0 + r) * 152 + c];
      }
    }
    __syncthreads();

    // ---- P2: h_p -> XB, h_q -> HQ for owned tiles
    if (wave < ntile) {
      const int n0 = (tile0 + wave) * 16;
      floatx4 accP = {0,0,0,0}, accQ = {0,0,0,0};
      const size_t wrow = (size_t)(n0 + l15) * KP + q * 8;
      const unsigned short* pP = ws + OFF_WP1  + wrow;
      const unsigned short* pQ = ws + OFF_WQ1D + wrow;
      const int aoff = l15 * PITCH + q * 8;
      #pragma unroll 4
      for (int ki = 0; ki < 19; ++ki) {
        short8 a = *(const short8*)(&DC[aoff + ki * 32]);
        accP = MFMA16(a, *(const short8*)(pP + ki * 32), accP, 0, 0, 0);
        accQ = MFMA16(a, *(const short8*)(pQ + ki * 32), accQ, 0, 0, 0);
      }
      const int col = n0 + l15;
      if (col < DDIM) {
        float bb = bp1[col];
        for (int i = 0; i < 4; ++i) {
          int row = q * 4 + i;
          XB[row * PITCH + col] = f2bf(elu_f(accP[i] + bb));
          float pre = bf2f(preq[((size_t)t * BATCH + brow0 + row) * 600 + col]);
          HQ[row * PITCH + col] = f2bf(elu_f(accQ[i] + pre));
        }
      }
    }
    __syncthreads();

    // ---- P3: head K-partials over owned cols -> PART[bg][slice][16][128]
    if (wave < 8) {
      const int h0 = wave * 16;                       // head rows: 0-63 prior, 64-127 post
      const unsigned short* Asrc = (wave < 4) ? XB : HQ;
      const int nk = (slice < 3) ? 5 : 4;             // 160 / 128 owned cols
      floatx4 acc = {0,0,0,0};
      const unsigned short* pW = ws + OFF_WHEAD + (size_t)(h0 + l15) * KP + cs + q * 8;
      const int abase = l15 * PITCH + cs + q * 8;
      for (int kk = 0; kk < nk; ++kk) {
        acc = MFMA16(*(const short8*)(&Asrc[abase + kk * 32]),
                     *(const short8*)(pW + kk * 32), acc, 0, 0, 0);
      }
      volatile float* pdst = (volatile float*)(PART + (size_t)(bg * 4 + slice) * (16 * 128));
      for (int i = 0; i < 4; ++i)
        pdst[(q * 4 + i) * 128 + h0 + l15] = acc[i];
    }
    bgsync();   // sync B: partials visible for next step's reduce
  }

  do_reduce(T_STEPS);   // emit final step's head outputs
}

extern "C" void kernel_launch(void* const* d_in, const int* in_sizes, int n_in,
                              void* d_out, int out_size, void* d_ws, size_t ws_size,
                              hipStream_t stream) {
  const float* enc    = (const float*)d_in[1];
  const float* act    = (const float*)d_in[2];
  const float* init_s = (const float*)d_in[3];
  const float* init_d = (const float*)d_in[4];
  const float* np_    = (const float*)d_in[5];
  const float* nq_    = (const float*)d_in[6];
  const float* Win    = (const float*)d_in[7];
  const float* b_in   = (const float*)d_in[8];
  const float* Wih    = (const float*)d_in[9];
  const float* Whh    = (const float*)d_in[10];
  const float* bih    = (const float*)d_in[11];
  const float* bhh    = (const float*)d_in[12];
  const float* Wp1    = (const float*)d_in[13];
  const float* bp1    = (const float*)d_in[14];
  const float* Wp2    = (const float*)d_in[15];
  const float* bp2    = (const float*)d_in[16];
  const float* Wq1    = (const float*)d_in[17];
  const float* bq1    = (const float*)d_in[18];
  const float* Wq2    = (const float*)d_in[19];
  const float* bq2    = (const float*)d_in[20];
  unsigned short* ws  = (unsigned short*)d_ws;
  float* out = (float*)d_out;

  stage_weights<<<dim3(256, 12), 256, 0, stream>>>(Win, Wih, Whh, Wp1, Wq1, Wp2, Wq2, ws);
  preq_gemm<<<3200, 256, 0, stream>>>(enc, bq1, ws, ws + OFF_PREQ);
  rssm_rollout<<<256, NTHREADS, 0, stream>>>(act, init_s, init_d, np_, nq_,
                                             b_in, bih, bhh, bp1, bp2, bq2, ws, out);
}

// Round 3
// 3618.256 us; speedup vs baseline: 1.9702x; 1.1124x over previous
//
#include <hip/hip_runtime.h>

#define MFMA16 __builtin_amdgcn_mfma_f32_16x16x32_bf16

typedef __attribute__((ext_vector_type(8))) short short8;
typedef __attribute__((ext_vector_type(4))) float floatx4;

static constexpr int T_STEPS = 50;
static constexpr int BATCH   = 1024;
static constexpr int SDIM    = 32;
static constexpr int DDIM    = 600;
static constexpr int ADIM    = 6;
static constexpr int KP      = 608;   // padded K/N per gate
static constexpr int PITCH   = 616;   // LDS row pitch (shorts)
static constexpr int SAPITCH = 72;
static constexpr int NWAVES  = 10;
static constexpr int NTHREADS = 640;

// workspace layout (ushort offsets)
static constexpr size_t SZ608    = (size_t)608 * 608;
static constexpr size_t OFF_WIHR = 0;
static constexpr size_t OFF_WIHZ = OFF_WIHR + SZ608;
static constexpr size_t OFF_WIHN = OFF_WIHZ + SZ608;
static constexpr size_t OFF_WHHR = OFF_WIHN + SZ608;
static constexpr size_t OFF_WHHZ = OFF_WHHR + SZ608;
static constexpr size_t OFF_WHHN = OFF_WHHZ + SZ608;
static constexpr size_t OFF_WP1  = OFF_WHHN + SZ608;
static constexpr size_t OFF_WQ1D = OFF_WP1  + SZ608;
static constexpr size_t OFF_WQ1E = OFF_WQ1D + SZ608;              // [608][1024]
static constexpr size_t OFF_WSA  = OFF_WQ1E + (size_t)608 * 1024; // [608][64]
static constexpr size_t OFF_WHEAD= OFF_WSA  + (size_t)608 * 64;   // [128][608]
static constexpr size_t OFF_PREQ = OFF_WHEAD+ (size_t)128 * 608;  // [50*1024][600] bf16
static constexpr size_t OFF_DETG = OFF_PREQ + (size_t)T_STEPS * BATCH * 600; // [1024][608] bf16
static constexpr size_t OFF_BAR  = OFF_DETG + (size_t)BATCH * KP;            // 64 ints
static constexpr size_t OFF_PART = OFF_BAR + 256;                 // [64][4][16][128] f32

// output offsets (fp32 elements), reference return order
static constexpr size_t O_PM = 0;
static constexpr size_t O_PS = 1638400;
static constexpr size_t O_PR = 3276800;
static constexpr size_t O_D1 = 4915200;
static constexpr size_t O_QM = 35635200;
static constexpr size_t O_QS = 37273600;
static constexpr size_t O_PO = 38912000;
static constexpr size_t O_D2 = 40550400;

__device__ __forceinline__ unsigned short f2bf(float f) {
  unsigned u = __float_as_uint(f);
  u += 0x7FFFu + ((u >> 16) & 1u);   // RNE
  return (unsigned short)(u >> 16);
}
__device__ __forceinline__ float bf2f(unsigned short u) {
  return __uint_as_float(((unsigned)u) << 16);
}
__device__ __forceinline__ float elu_f(float v) { return v > 0.f ? v : expm1f(v); }
__device__ __forceinline__ float sigmoid_f(float x) { return 1.f / (1.f + expf(-x)); }
__device__ __forceinline__ float tanh_f(float x) {
  x = fminf(fmaxf(x, -15.f), 15.f);
  float e = expf(2.f * x);
  return (e - 1.f) / (e + 1.f);
}

// ---------------- prep: stage weights as bf16, padded/split per gate ----------------
__global__ __launch_bounds__(256) void stage_weights(
    const float* __restrict__ Win, const float* __restrict__ Wih, const float* __restrict__ Whh,
    const float* __restrict__ Wp1, const float* __restrict__ Wq1,
    const float* __restrict__ Wp2, const float* __restrict__ Wq2,
    unsigned short* __restrict__ ws)
{
  const int region = blockIdx.y;
  if (region == 11) {           // zero the per-bgroup barrier counters each launch
    if (blockIdx.x == 0 && threadIdx.x < 64)
      ((int*)(ws + OFF_BAR))[threadIdx.x] = 0;
    return;
  }
  int R = 608, C = 608;
  size_t dst = 0;
  switch (region) {
    case 0: dst = OFF_WIHR; break;
    case 1: dst = OFF_WIHZ; break;
    case 2: dst = OFF_WIHN; break;
    case 3: dst = OFF_WHHR; break;
    case 4: dst = OFF_WHHZ; break;
    case 5: dst = OFF_WHHN; break;
    case 6: dst = OFF_WP1;  break;
    case 7: dst = OFF_WQ1D; break;
    case 8: dst = OFF_WQ1E; C = 1024; break;
    case 9: dst = OFF_WSA;  C = 64;   break;
    case 10: dst = OFF_WHEAD; R = 128; break;
  }
  const int total = R * C;
  for (int e = blockIdx.x * 256 + threadIdx.x; e < total; e += gridDim.x * 256) {
    int n = e / C, k = e - n * C;
    float v = 0.f;
    switch (region) {
      case 0: if (n < 600 && k < 600) v = Wih[(size_t)n * 600 + k]; break;
      case 1: if (n < 600 && k < 600) v = Wih[(size_t)(600 + n) * 600 + k]; break;
      case 2: if (n < 600 && k < 600) v = Wih[(size_t)(1200 + n) * 600 + k]; break;
      case 3: if (n < 600 && k < 600) v = Whh[(size_t)n * 600 + k]; break;
      case 4: if (n < 600 && k < 600) v = Whh[(size_t)(600 + n) * 600 + k]; break;
      case 5: if (n < 600 && k < 600) v = Whh[(size_t)(1200 + n) * 600 + k]; break;
      case 6: if (n < 600 && k < 600) v = Wp1[(size_t)n * 600 + k]; break;
      case 7: if (n < 600 && k < 600) v = Wq1[(size_t)n * 1624 + k]; break;
      case 8: if (n < 600) v = Wq1[(size_t)n * 1624 + 600 + k]; break;
      case 9: if (n < 600) { if (k < 32) v = Win[(size_t)n * 38 + 6 + k];
                             else if (k < 38) v = Win[(size_t)n * 38 + (k - 32)]; } break;
      case 10: if (k < 600) v = (n < 64) ? Wp2[(size_t)n * 600 + k]
                                         : Wq2[(size_t)(n - 64) * 600 + k]; break;
    }
    ws[dst + (size_t)e] = f2bf(v);
  }
}

// ---------------- prep: pre_q[t,b,:] = enc[t,b,:] @ Wq1[:,600:].T + bq1 (bf16 out) ----------------
__global__ __launch_bounds__(256) void preq_gemm(
    const float* __restrict__ enc, const float* __restrict__ bq1,
    const unsigned short* __restrict__ ws, unsigned short* __restrict__ preq)
{
  __shared__ unsigned short A[16 * 1032];
  const size_t g0 = (size_t)blockIdx.x * 16;
  const int tid = threadIdx.x;

  const float4* e4 = (const float4*)(enc + g0 * 1024);
  for (int i = tid; i < 16 * 256; i += 256) {
    int row = i >> 8, c4 = i & 255;
    float4 v = e4[row * 256 + c4];
    int base = row * 1032 + c4 * 4;
    A[base + 0] = f2bf(v.x); A[base + 1] = f2bf(v.y);
    A[base + 2] = f2bf(v.z); A[base + 3] = f2bf(v.w);
  }
  __syncthreads();

  const int wave = tid >> 6, lane = tid & 63, q = lane >> 4, l15 = lane & 15;
  const unsigned short* Wq1e = ws + OFF_WQ1E;
  for (int tile = wave; tile < 38; tile += 4) {
    const int n0 = tile * 16;
    floatx4 acc = {0.f, 0.f, 0.f, 0.f};
    const unsigned short* wb = Wq1e + (size_t)(n0 + l15) * 1024 + q * 8;
    const int aoff = l15 * 1032 + q * 8;
    for (int ki = 0; ki < 32; ++ki) {
      short8 a = *(const short8*)(&A[aoff + ki * 32]);
      short8 b = *(const short8*)(wb + ki * 32);
      acc = MFMA16(a, b, acc, 0, 0, 0);
    }
    const int col = n0 + l15;
    if (col < 600) {
      float bb = bq1[col];
      for (int i = 0; i < 4; ++i) {
        int row = q * 4 + i;
        preq[(g0 + row) * 600 + col] = f2bf(acc[i] + bb);
      }
    }
  }
}

// ---------------- main rollout: 256 wgs = 64 batch-groups x 4 N-slices ----------------
// slice = wgid & 3  -> each XCD hosts exactly one slice's weights (L2-resident).
// Cross-XCD traffic (DETG, PART) is volatile (LLC-coherent); barrier flags are RELAXED
// agent-scope atomics (no cache-maintenance). Inner K-loops are hand software-pipelined
// with named register buffers (depth 2-3) so all weight loads of an iteration are in
// flight simultaneously -- the round-2 kernel at VGPR=80 serialized them one-by-one.
__global__ __launch_bounds__(NTHREADS)
__attribute__((amdgpu_waves_per_eu(2)))
void rssm_rollout(
    const float* __restrict__ actions, const float* __restrict__ init_stoch,
    const float* __restrict__ init_det,
    const float* __restrict__ eps_p, const float* __restrict__ eps_q,
    const float* __restrict__ b_in, const float* __restrict__ b_ih, const float* __restrict__ b_hh,
    const float* __restrict__ bp1, const float* __restrict__ bp2, const float* __restrict__ bq2,
    unsigned short* __restrict__ wsm, float* __restrict__ out)
{
  __shared__ unsigned short XB[16 * PITCH];   // rnn_in; overwritten with h_p in P2
  __shared__ unsigned short DC[16 * PITCH];   // det (old; refreshed to det_new after sync A)
  __shared__ unsigned short HQ[16 * PITCH];   // h_q
  __shared__ unsigned short SA[16 * SAPITCH]; // [stoch(32)|act(6)|pad] bf16

  const unsigned short* ws = wsm;
  const int tid  = threadIdx.x;
  const int wave = tid >> 6, lane = tid & 63, q = lane >> 4, l15 = lane & 15;
  const int wg    = blockIdx.x;
  const int slice = wg & 3;
  const int bg    = wg >> 2;
  const int brow0 = bg * 16;
  const int ntile = (slice < 3) ? 10 : 8;     // col tiles: contiguous 10/10/10/8 (= 38)
  const int tile0 = slice * 10;
  const int cs    = slice * 160;              // owned col base

  unsigned short* DETG = wsm + OFF_DETG;
  int*   bar  = (int*)(wsm + OFF_BAR);
  float* PART = (float*)(wsm + OFF_PART);
  const unsigned short* preq = ws + OFF_PREQ;

  float* out_pm = out + O_PM; float* out_ps = out + O_PS; float* out_pr = out + O_PR;
  float* out_d1 = out + O_D1; float* out_qm = out + O_QM; float* out_qs = out + O_QS;
  float* out_po = out + O_PO; float* out_d2 = out + O_D2;

  int phase = 0;
  auto bgsync = [&]() {   // 4-wg barrier per batch-group, RELAXED (no cache maintenance).
    __syncthreads();
    ++phase;
    if (tid == 0) {
      __hip_atomic_fetch_add(&bar[bg], 1, __ATOMIC_RELAXED, __HIP_MEMORY_SCOPE_AGENT);
      while (__hip_atomic_load(&bar[bg], __ATOMIC_RELAXED, __HIP_MEMORY_SCOPE_AGENT) < 4 * phase)
        __builtin_amdgcn_s_sleep(2);
    }
    __syncthreads();
    asm volatile("" ::: "memory");
  };

  auto do_reduce = [&](int tcur) {  // combine head partials of step (tcur-1); fill SA; write outs
    const volatile float* part = (const volatile float*)(PART + (size_t)bg * (4 * 16 * 128));
    if (tid < 512) {
      const int r = tid >> 5, c = tid & 31;
      const volatile float* p0 = part + (0 * 16 + r) * 128;
      const volatile float* p1 = part + (1 * 16 + r) * 128;
      const volatile float* p2 = part + (2 * 16 + r) * 128;
      const volatile float* p3 = part + (3 * 16 + r) * 128;
      // issue all 16 loads before any use
      float a00 = p0[c], a01 = p0[32 + c], a02 = p0[64 + c], a03 = p0[96 + c];
      float a10 = p1[c], a11 = p1[32 + c], a12 = p1[64 + c], a13 = p1[96 + c];
      float a20 = p2[c], a21 = p2[32 + c], a22 = p2[64 + c], a23 = p2[96 + c];
      float a30 = p3[c], a31 = p3[32 + c], a32 = p3[64 + c], a33 = p3[96 + c];
      float pm  = bp2[c]      + a00 + a10 + a20 + a30;
      float psr = bp2[32 + c] + a01 + a11 + a21 + a31;
      float qm  = bq2[c]      + a02 + a12 + a22 + a32;
      float qsr = bq2[32 + c] + a03 + a13 + a23 + a33;
      const size_t oidx = ((size_t)(tcur - 1) * BATCH + brow0 + r) * SDIM + c;
      const float qs = (qsr > 30.f ? qsr : log1pf(expf(qsr))) + 0.1f;
      const float x  = qm + qs * eps_q[oidx];
      SA[r * SAPITCH + c] = f2bf(x);          // stoch carry
      if (slice == 0) {
        const float ps = (psr > 30.f ? psr : log1pf(expf(psr))) + 0.1f;
        __builtin_nontemporal_store(pm, &out_pm[oidx]);
        __builtin_nontemporal_store(ps, &out_ps[oidx]);
        __builtin_nontemporal_store(pm + ps * eps_p[oidx], &out_pr[oidx]);
      } else if (slice == 1) {
        __builtin_nontemporal_store(qm, &out_qm[oidx]);
        __builtin_nontemporal_store(qs, &out_qs[oidx]);
        __builtin_nontemporal_store(x,  &out_po[oidx]);
      }
    }
  };

  for (int t = 0; t < T_STEPS; ++t) {
    // ---- top of step: SA fill (init or reduce of prev heads) + stage act[t]
    if (t == 0) {
      for (int i = tid; i < 16 * PITCH; i += NTHREADS) { XB[i] = 0; DC[i] = 0; HQ[i] = 0; }
      for (int i = tid; i < 16 * SAPITCH; i += NTHREADS) SA[i] = 0;
      __syncthreads();
      for (int i = tid; i < 16 * SDIM; i += NTHREADS) {
        int r = i >> 5, c = i & 31;
        SA[r * SAPITCH + c] = f2bf(init_stoch[(size_t)(brow0 + r) * SDIM + c]);
      }
      for (int i = tid; i < 16 * DDIM; i += NTHREADS) {
        int r = i / DDIM, k = i - r * DDIM;
        DC[r * PITCH + k] = f2bf(init_det[(size_t)(brow0 + r) * DDIM + k]);
      }
      if (tid < 128) {  // zero DETG pad cols (600..607) for this bgroup
        int r = tid >> 3, c = 600 + (tid & 7);
        *(volatile unsigned short*)&DETG[(size_t)(brow0 + r) * KP + c] = 0;
      }
    } else {
      do_reduce(t);
    }
    if (tid < 96) {
      int r = tid / 6, j = tid - r * 6;
      SA[r * SAPITCH + 32 + j] = f2bf(actions[((size_t)t * BATCH + brow0 + r) * ADIM + j]);
    }
    __syncthreads();

    // ---- P0b: rnn_in = elu([stoch|act] @ Wsa.T + b_in) -> XB, full width (cheap, redundant)
    for (int tile = wave; tile < 38; tile += NWAVES) {
      const int n0 = tile * 16;
      floatx4 acc = {0.f, 0.f, 0.f, 0.f};
      const unsigned short* wb = ws + OFF_WSA + (size_t)(n0 + l15) * 64 + q * 8;
      const int aoff = l15 * SAPITCH + q * 8;
      short8 a0 = *(const short8*)(&SA[aoff]);
      short8 a1 = *(const short8*)(&SA[aoff + 32]);
      short8 b0 = *(const short8*)(wb);
      short8 b1 = *(const short8*)(wb + 32);
      acc = MFMA16(a0, b0, acc, 0, 0, 0);
      acc = MFMA16(a1, b1, acc, 0, 0, 0);
      const int col = n0 + l15;
      if (col < DDIM) {
        float bi = b_in[col];
        for (int i = 0; i < 4; ++i)
          XB[(q * 4 + i) * PITCH + col] = f2bf(elu_f(acc[i] + bi));
      }
    }
    __syncthreads();

    // ---- P1: GRU for owned col tiles -> DETG + outputs d1/d2 (depth-2 reg pipeline)
    if (wave < ntile) {
      const int n0 = (tile0 + wave) * 16;
      floatx4 aIr = {0,0,0,0}, aIz = {0,0,0,0}, aIn = {0,0,0,0};
      floatx4 aHr = {0,0,0,0}, aHz = {0,0,0,0}, aHn = {0,0,0,0};
      const size_t wrow = (size_t)(n0 + l15) * KP + q * 8;
      const unsigned short* pIr = ws + OFF_WIHR + wrow;
      const unsigned short* pIz = ws + OFF_WIHZ + wrow;
      const unsigned short* pIn = ws + OFF_WIHN + wrow;
      const unsigned short* pHr = ws + OFF_WHHR + wrow;
      const unsigned short* pHz = ws + OFF_WHHZ + wrow;
      const unsigned short* pHn = ws + OFF_WHHN + wrow;
      const int aoff = l15 * PITCH + q * 8;
      short8 cIr, cIz, cIn, cHr, cHz, cHn;   // current K-slice B operands
      short8 nIr, nIz, nIn, nHr, nHz, nHn;   // next K-slice (prefetch)
      cIr = *(const short8*)(pIr); cIz = *(const short8*)(pIz); cIn = *(const short8*)(pIn);
      cHr = *(const short8*)(pHr); cHz = *(const short8*)(pHz); cHn = *(const short8*)(pHn);
      #pragma unroll
      for (int ki = 0; ki < 19; ++ki) {
        if (ki < 18) {
          const int o = (ki + 1) * 32;
          nIr = *(const short8*)(pIr + o); nIz = *(const short8*)(pIz + o);
          nIn = *(const short8*)(pIn + o); nHr = *(const short8*)(pHr + o);
          nHz = *(const short8*)(pHz + o); nHn = *(const short8*)(pHn + o);
        }
        short8 ax = *(const short8*)(&XB[aoff + ki * 32]);
        short8 ad = *(const short8*)(&DC[aoff + ki * 32]);
        aIr = MFMA16(ax, cIr, aIr, 0, 0, 0);
        aIz = MFMA16(ax, cIz, aIz, 0, 0, 0);
        aIn = MFMA16(ax, cIn, aIn, 0, 0, 0);
        aHr = MFMA16(ad, cHr, aHr, 0, 0, 0);
        aHz = MFMA16(ad, cHz, aHz, 0, 0, 0);
        aHn = MFMA16(ad, cHn, aHn, 0, 0, 0);
        cIr = nIr; cIz = nIz; cIn = nIn; cHr = nHr; cHz = nHz; cHn = nHn;
      }
      const int d = n0 + l15;
      if (d < DDIM) {
        float bihr = b_ih[d],        bhhr = b_hh[d];
        float bihz = b_ih[600 + d],  bhhz = b_hh[600 + d];
        float bihn = b_ih[1200 + d], bhhn = b_hh[1200 + d];
        for (int i = 0; i < 4; ++i) {
          int row = q * 4 + i;
          float r = sigmoid_f(aIr[i] + aHr[i] + bihr + bhhr);
          float z = sigmoid_f(aIz[i] + aHz[i] + bihz + bhhz);
          float n = tanh_f(aIn[i] + bihn + r * (aHn[i] + bhhn));
          float dprev = bf2f(DC[row * PITCH + d]);
          float dn = (1.f - z) * n + z * dprev;
          *(volatile unsigned short*)&DETG[(size_t)(brow0 + row) * KP + d] = f2bf(dn);
          size_t oidx = ((size_t)t * BATCH + brow0 + row) * DDIM + d;
          __builtin_nontemporal_store(dn, &out_d1[oidx]);
          __builtin_nontemporal_store(dn, &out_d2[oidx]);
        }
      }
    }
    bgsync();   // sync A: det_new complete across the bgroup's 4 slices

    // ---- load full det_new -> DC (all 4 volatile loads in flight, then store)
    {
      const volatile unsigned long long* src =
          (const volatile unsigned long long*)DETG;   // 608 shorts = 152 x 8B per row
      const int i0 = tid, i1 = tid + 640, i2 = tid + 1280, i3 = tid + 1920;
      const int r0 = i0 / 152, c0 = i0 - r0 * 152;
      const int r1 = i1 / 152, c1 = i1 - r1 * 152;
      const int r2 = i2 / 152, c2 = i2 - r2 * 152;
      const int r3 = i3 / 152, c3 = i3 - r3 * 152;
      unsigned long long v0, v1, v2, v3 = 0;
      v0 = src[(size_t)(brow0 + r0) * 152 + c0];
      v1 = src[(size_t)(brow0 + r1) * 152 + c1];
      v2 = src[(size_t)(brow0 + r2) * 152 + c2];
      if (i3 < 2432) v3 = src[(size_t)(brow0 + r3) * 152 + c3];
      *(unsigned long long*)(&DC[r0 * PITCH + c0 * 4]) = v0;
      *(unsigned long long*)(&DC[r1 * PITCH + c1 * 4]) = v1;
      *(unsigned long long*)(&DC[r2 * PITCH + c2 * 4]) = v2;
      if (i3 < 2432) *(unsigned long long*)(&DC[r3 * PITCH + c3 * 4]) = v3;
    }
    __syncthreads();

    // ---- P2: h_p -> XB, h_q -> HQ for owned tiles (depth-3 reg pipeline)
    if (wave < ntile) {
      const int n0 = (tile0 + wave) * 16;
      floatx4 accP = {0,0,0,0}, accQ = {0,0,0,0};
      const size_t wrow = (size_t)(n0 + l15) * KP + q * 8;
      const unsigned short* pP = ws + OFF_WP1  + wrow;
      const unsigned short* pQ = ws + OFF_WQ1D + wrow;
      const int aoff = l15 * PITCH + q * 8;
      short8 b0P, b0Q, b1P, b1Q, b2P, b2Q;
      b0P = *(const short8*)(pP);      b0Q = *(const short8*)(pQ);
      b1P = *(const short8*)(pP + 32); b1Q = *(const short8*)(pQ + 32);
      #pragma unroll
      for (int ki = 0; ki < 19; ++ki) {
        if (ki < 17) {
          const int o = (ki + 2) * 32;
          b2P = *(const short8*)(pP + o); b2Q = *(const short8*)(pQ + o);
        }
        short8 a = *(const short8*)(&DC[aoff + ki * 32]);
        accP = MFMA16(a, b0P, accP, 0, 0, 0);
        accQ = MFMA16(a, b0Q, accQ, 0, 0, 0);
        b0P = b1P; b0Q = b1Q; b1P = b2P; b1Q = b2Q;
      }
      const int col = n0 + l15;
      if (col < DDIM) {
        float bb = bp1[col];
        for (int i = 0; i < 4; ++i) {
          int row = q * 4 + i;
          XB[row * PITCH + col] = f2bf(elu_f(accP[i] + bb));
          float pre = bf2f(__builtin_nontemporal_load(
              &preq[((size_t)t * BATCH + brow0 + row) * 600 + col]));
          HQ[row * PITCH + col] = f2bf(elu_f(accQ[i] + pre));
        }
      }
    }
    __syncthreads();

    // ---- P3: head K-partials over owned cols -> PART[bg][slice][16][128] (preload all)
    if (wave < 8) {
      const int h0 = wave * 16;                       // head rows: 0-63 prior, 64-127 post
      const unsigned short* Asrc = (wave < 4) ? XB : HQ;
      floatx4 acc = {0,0,0,0};
      const unsigned short* pW = ws + OFF_WHEAD + (size_t)(h0 + l15) * KP + cs + q * 8;
      const int abase = l15 * PITCH + cs + q * 8;
      short8 w0, w1, w2, w3, w4 = {};
      short8 a0, a1, a2, a3, a4 = {};
      w0 = *(const short8*)(pW);       w1 = *(const short8*)(pW + 32);
      w2 = *(const short8*)(pW + 64);  w3 = *(const short8*)(pW + 96);
      a0 = *(const short8*)(&Asrc[abase]);      a1 = *(const short8*)(&Asrc[abase + 32]);
      a2 = *(const short8*)(&Asrc[abase + 64]); a3 = *(const short8*)(&Asrc[abase + 96]);
      if (slice < 3) {
        w4 = *(const short8*)(pW + 128);
        a4 = *(const short8*)(&Asrc[abase + 128]);
      }
      acc = MFMA16(a0, w0, acc, 0, 0, 0);
      acc = MFMA16(a1, w1, acc, 0, 0, 0);
      acc = MFMA16(a2, w2, acc, 0, 0, 0);
      acc = MFMA16(a3, w3, acc, 0, 0, 0);
      if (slice < 3) acc = MFMA16(a4, w4, acc, 0, 0, 0);
      volatile float* pdst = (volatile float*)(PART + (size_t)(bg * 4 + slice) * (16 * 128));
      for (int i = 0; i < 4; ++i)
        pdst[(q * 4 + i) * 128 + h0 + l15] = acc[i];
    }
    bgsync();   // sync B: partials visible for next step's reduce
  }

  do_reduce(T_STEPS);   // emit final step's head outputs
}

extern "C" void kernel_launch(void* const* d_in, const int* in_sizes, int n_in,
                              void* d_out, int out_size, void* d_ws, size_t ws_size,
                              hipStream_t stream) {
  const float* enc    = (const float*)d_in[1];
  const float* act    = (const float*)d_in[2];
  const float* init_s = (const float*)d_in[3];
  const float* init_d = (const float*)d_in[4];
  const float* np_    = (const float*)d_in[5];
  const float* nq_    = (const float*)d_in[6];
  const float* Win    = (const float*)d_in[7];
  const float* b_in   = (const float*)d_in[8];
  const float* Wih    = (const float*)d_in[9];
  const float* Whh    = (const float*)d_in[10];
  const float* bih    = (const float*)d_in[11];
  const float* bhh    = (const float*)d_in[12];
  const float* Wp1    = (const float*)d_in[13];
  const float* bp1    = (const float*)d_in[14];
  const float* Wp2    = (const float*)d_in[15];
  const float* bp2    = (const float*)d_in[16];
  const float* Wq1    = (const float*)d_in[17];
  const float* bq1    = (const float*)d_in[18];
  const float* Wq2    = (const float*)d_in[19];
  const float* bq2    = (const float*)d_in[20];
  unsigned short* ws  = (unsigned short*)d_ws;
  float* out = (float*)d_out;

  stage_weights<<<dim3(256, 12), 256, 0, stream>>>(Win, Wih, Whh, Wp1, Wq1, Wp2, Wq2, ws);
  preq_gemm<<<3200, 256, 0, stream>>>(enc, bq1, ws, ws + OFF_PREQ);
  rssm_rollout<<<256, NTHREADS, 0, stream>>>(act, init_s, init_d, np_, nq_,
                                             b_in, bih, bhh, bp1, bp2, bq2, ws, out);
}